// Round 1
// baseline (1108.475 us; speedup 1.0000x reference)
//
#include <hip/hip_runtime.h>

#define N_ROWS 100000
#define HID 256
#define NCLASS 64
#define KPAD 2816
#define NTILE 44
#define BN_EPS 1e-5f

typedef unsigned short u16;
typedef __bf16 bf16x8 __attribute__((ext_vector_type(8)));
typedef float floatx4 __attribute__((ext_vector_type(4)));
typedef float f32x4u __attribute__((ext_vector_type(4), aligned(4)));

union FragU { bf16x8 v; uint4 u; u16 s[8]; };
union BfBits { __bf16 b; u16 s; };

struct GemmArgs {
    const float* feat[8];
    const float* emb[8];
};

// padded-K channel offsets (each channel padded to multiple of 64)
// dims {334,512,128,745,256,600,64,64} -> pads {384,512,128,768,256,640,64,64}
__constant__ int c_POFF[9] = {0, 384, 896, 1024, 1792, 2048, 2688, 2752, 2816};
__constant__ int c_KDIM[8] = {334, 512, 128, 745, 256, 600, 64, 64};

// ---------------- prep 0: gate probs + zero global stats ----------------
__global__ void k_prep0(const float* __restrict__ alpha, const float* __restrict__ gumbels,
                        const int* __restrict__ es, float* __restrict__ wsf) {
    int tid = threadIdx.x;
    if (tid < 128) wsf[8 + tid] = 0.f;   // gstats[128] at wsf+8
    if (tid == 0) {
        float w[8], mx = -1e30f;
        for (int i = 0; i < 8; ++i) { w[i] = alpha[es[i]]; mx = fmaxf(mx, w[i]); }
        float se = 0.f;
        for (int i = 0; i < 8; ++i) se += expf(w[i] - mx);
        float lse = logf(se) + mx;
        float t[8], mt = -1e30f;
        for (int i = 0; i < 8; ++i) { t[i] = (w[i] - lse + gumbels[i]); mt = fmaxf(mt, t[i]); } // TAU=1
        float p[8], ss = 0.f;
        for (int i = 0; i < 8; ++i) { p[i] = expf(t[i] - mt); ss += p[i]; }
        for (int i = 0; i < 8; ++i) wsf[i] = p[i] / ss;
    }
}

// ---------------- prep 1: build WcT[256][KPAD] bf16 (scaled, transposed, zero-padded)
//                  and wT[64][256] bf16 copy of w_out ----------------
__global__ __launch_bounds__(256) void k_prep1(GemmArgs ga, const float* __restrict__ w_out,
                                               const float* __restrict__ wsf,
                                               u16* __restrict__ WcT, u16* __restrict__ wT) {
    int bx = blockIdx.x, tid = threadIdx.x;
    if (bx < KPAD) {
        int kp = bx, n = tid;
        int c = 0;
        #pragma unroll
        for (int i = 1; i < 8; ++i) c += (kp >= c_POFF[i]);
        int l = kp - c_POFF[c];
        float v = 0.f;
        if (l < c_KDIM[c]) v = wsf[c] * ga.emb[c][l * HID + n];
        BfBits u; u.b = (__bf16)v;
        WcT[n * KPAD + kp] = u.s;
    } else {
        int cls = bx - KPAD;
        BfBits u; u.b = (__bf16)w_out[cls * HID + tid];
        wT[cls * HID + tid] = u.s;
    }
}

// ---------------- GEMM1 (64x256 tile) + PReLU + GEMM2 (x @ w_out^T) + stats ----------------
__global__ __launch_bounds__(256) void k_gemm1(GemmArgs ga, const u16* __restrict__ WcT,
                                               const u16* __restrict__ wT,
                                               const float* __restrict__ prelu_a,
                                               float* __restrict__ out,
                                               float* __restrict__ gstats) {
    __shared__ __align__(16) char smA[8192];    // A tile: 64 rows x 64 k bf16, octet-swizzled
    __shared__ __align__(16) char smB[32768];   // B tile: [n=256][octet 0..7] 16B chunks; reused as h[64][256]
    __shared__ float sstats[128];

    const int tid = threadIdx.x;
    const int lane = tid & 63;
    const int quad = lane >> 4;
    const int l15 = lane & 15;
    const int wave = tid >> 6;
    const int row0 = blockIdx.x * 64;

    if (tid < 128) sstats[tid] = 0.f;

    floatx4 acc[4][4];
    #pragma unroll
    for (int i = 0; i < 4; ++i)
        #pragma unroll
        for (int j = 0; j < 4; ++j)
            acc[i][j] = (floatx4){0.f, 0.f, 0.f, 0.f};

    for (int t = 0; t < NTILE; ++t) {
        const int k0 = t * 64;
        int c = 0;
        #pragma unroll
        for (int i = 1; i < 8; ++i) c += (k0 >= c_POFF[i]);
        const int Kc = c_KDIM[c];
        const int lkb = k0 - c_POFF[c];
        const float* fp_base = ga.feat[c];

        // ---- stage A: 512 octets (64 rows x 8 octets), 2 per thread, fp32->bf16
        #pragma unroll
        for (int i = 0; i < 2; ++i) {
            int o = tid + i * 256;
            int row = o >> 3, oct = o & 7;
            int r = row0 + row;
            int lk = lkb + oct * 8;
            const float* fp = fp_base + r * Kc + lk;
            float vv[8];
            if (r < N_ROWS && lk + 8 <= Kc) {
                f32x4u a0 = *(const f32x4u*)fp;
                f32x4u a1 = *(const f32x4u*)(fp + 4);
                vv[0] = a0.x; vv[1] = a0.y; vv[2] = a0.z; vv[3] = a0.w;
                vv[4] = a1.x; vv[5] = a1.y; vv[6] = a1.z; vv[7] = a1.w;
            } else {
                #pragma unroll
                for (int j = 0; j < 8; ++j)
                    vv[j] = (r < N_ROWS && lk + j < Kc) ? fp[j] : 0.f;
            }
            FragU f;
            #pragma unroll
            for (int j = 0; j < 8; ++j) f.v[j] = (__bf16)vv[j];
            *(uint4*)(smA + row * 128 + ((oct ^ (row & 7)) << 4)) = f.u;
        }

        // ---- stage B: 2048 16B chunks of WcT tile, 8 per thread, swizzled gather
        const u16* WcTk = WcT + k0;
        #pragma unroll
        for (int it = 0; it < 8; ++it) {
            int ci = tid + it * 256;          // 0..2047
            int n = ci >> 3, osl = ci & 7;
            int osrc = osl ^ (n & 7);
            uint4 d = *(const uint4*)(WcTk + n * KPAD + osrc * 8);
            *(uint4*)(smB + ci * 16) = d;
        }
        __syncthreads();

        // ---- compute: 2 k-steps of 32, 16 MFMA each per wave
        #pragma unroll
        for (int ks = 0; ks < 2; ++ks) {
            int oct = ks * 4 + quad;
            FragU af[4], bfr[4];
            #pragma unroll
            for (int mf = 0; mf < 4; ++mf) {
                int m = mf * 16 + l15;
                af[mf].u = *(const uint4*)(smA + m * 128 + ((oct ^ (m & 7)) << 4));
            }
            #pragma unroll
            for (int nf = 0; nf < 4; ++nf) {
                int n = wave * 64 + nf * 16 + l15;
                bfr[nf].u = *(const uint4*)(smB + n * 128 + ((oct ^ (n & 7)) << 4));
            }
            #pragma unroll
            for (int mf = 0; mf < 4; ++mf)
                #pragma unroll
                for (int nf = 0; nf < 4; ++nf)
                    acc[mf][nf] = __builtin_amdgcn_mfma_f32_16x16x32_bf16(
                        af[mf].v, bfr[nf].v, acc[mf][nf], 0, 0, 0);
        }
        __syncthreads();
    }

    // ---- epilogue: PReLU, h -> LDS (A-operand layout, swizzled), C/D layout: col=l15, row=quad*4+r
    const float slope = prelu_a[0];
    #pragma unroll
    for (int nf = 0; nf < 4; ++nf) {
        int colg = wave * 64 + nf * 16 + l15;   // k index of h
        int oct = colg >> 3, sub = colg & 7;
        #pragma unroll
        for (int mf = 0; mf < 4; ++mf) {
            #pragma unroll
            for (int r = 0; r < 4; ++r) {
                int row = mf * 16 + quad * 4 + r;
                float x = acc[mf][nf][r];
                float hx = x >= 0.f ? x : slope * x;
                BfBits u; u.b = (__bf16)hx;
                *(u16*)(smB + row * 512 + ((oct ^ (row & 7)) << 4) + sub * 2) = u.s;
            }
        }
    }
    __syncthreads();

    // ---- GEMM2: z[64 x 64] = h @ w_out^T ; wave w owns rows [16w,16w+16)
    floatx4 acc2[4];
    #pragma unroll
    for (int i = 0; i < 4; ++i) acc2[i] = (floatx4){0.f, 0.f, 0.f, 0.f};
    {
        int m = wave * 16 + l15;
        #pragma unroll
        for (int ks = 0; ks < 8; ++ks) {
            int oct = ks * 4 + quad;
            FragU ah;
            ah.u = *(const uint4*)(smB + m * 512 + ((oct ^ (m & 7)) << 4));
            #pragma unroll
            for (int nf = 0; nf < 4; ++nf) {
                int cls = nf * 16 + l15;
                FragU bw;
                bw.u = *(const uint4*)(wT + cls * HID + oct * 8);
                acc2[nf] = __builtin_amdgcn_mfma_f32_16x16x32_bf16(ah.v, bw.v, acc2[nf], 0, 0, 0);
            }
        }
    }

    // ---- store z + per-class partial sums
    #pragma unroll
    for (int nf = 0; nf < 4; ++nf) {
        int cls = nf * 16 + l15;
        float s1 = 0.f, s2 = 0.f;
        #pragma unroll
        for (int r = 0; r < 4; ++r) {
            int row = wave * 16 + quad * 4 + r;
            int grow = row0 + row;
            float z = acc2[nf][r];
            if (grow < N_ROWS) out[grow * NCLASS + cls] = z;
            s1 += z; s2 += z * z;   // invalid rows give z==0
        }
        s1 += __shfl_xor(s1, 16); s1 += __shfl_xor(s1, 32);
        s2 += __shfl_xor(s2, 16); s2 += __shfl_xor(s2, 32);
        if (quad == 0) {
            atomicAdd(&sstats[cls], s1);
            atomicAdd(&sstats[64 + cls], s2);
        }
    }
    __syncthreads();
    if (tid < 128) atomicAdd(&gstats[tid], sstats[tid]);
}

// ---------------- stats finalize: sums -> mean / invstd ----------------
__global__ void k_stats(float* __restrict__ wsf) {
    int c = threadIdx.x;
    if (c < 64) {
        float s1 = wsf[8 + c], s2 = wsf[8 + 64 + c];
        float mean = s1 * (1.f / N_ROWS);
        float var = s2 * (1.f / N_ROWS) - mean * mean;
        wsf[8 + c] = mean;
        wsf[8 + 64 + c] = rsqrtf(var + BN_EPS);
    }
}

// ---------------- normalize in place ----------------
__global__ __launch_bounds__(256) void k_norm(float* __restrict__ out, const float* __restrict__ wsf) {
    int idx = blockIdx.x * 256 + threadIdx.x;
    int base = idx * 4;
    int c0 = base & 63;
    floatx4 v = *(floatx4*)(out + base);
    #pragma unroll
    for (int j = 0; j < 4; ++j) {
        float mean = wsf[8 + c0 + j];
        float inv  = wsf[72 + c0 + j];
        v[j] = (v[j] - mean) * inv;
    }
    *(floatx4*)(out + base) = v;
}

extern "C" void kernel_launch(void* const* d_in, const int* in_sizes, int n_in,
                              void* d_out, int out_size, void* d_ws, size_t ws_size,
                              hipStream_t stream) {
    // dict order: feat0,emb0,...,feat5,emb5, lab0,lemb0, lab1,lemb1,
    //             alpha(16), gumbels(17), prelu_a(18), w_out(19), epoch_sampled(20)
    GemmArgs ga;
    const int fidx[8] = {0, 2, 4, 6, 8, 10, 12, 14};
    const int eidx[8] = {1, 3, 5, 7, 9, 11, 13, 15};
    for (int i = 0; i < 8; ++i) {
        ga.feat[i] = (const float*)d_in[fidx[i]];
        ga.emb[i]  = (const float*)d_in[eidx[i]];
    }
    const float* alpha   = (const float*)d_in[16];
    const float* gumbels = (const float*)d_in[17];
    const float* prelu_a = (const float*)d_in[18];
    const float* w_out   = (const float*)d_in[19];
    const int*   es      = (const int*)d_in[20];

    float* wsf = (float*)d_ws;                              // probs[8] + gstats[128]
    u16* WcT = (u16*)((char*)d_ws + 1024);                  // [256][KPAD] bf16
    u16* wT  = (u16*)((char*)d_ws + 1024 + (size_t)KPAD * 256 * 2);  // [64][256] bf16
    float* out = (float*)d_out;

    k_prep0<<<1, 256, 0, stream>>>(alpha, gumbels, es, wsf);
    k_prep1<<<KPAD + NCLASS, 256, 0, stream>>>(ga, w_out, wsf, WcT, wT);
    k_gemm1<<<(N_ROWS + 63) / 64, 256, 0, stream>>>(ga, WcT, wT, prelu_a, out, wsf + 8);
    k_stats<<<1, 64, 0, stream>>>(wsf);
    k_norm<<<(N_ROWS * NCLASS) / 1024, 256, 0, stream>>>(out, wsf);
}